// Round 8
// baseline (447.406 us; speedup 1.0000x reference)
//
#include <hip/hip_runtime.h>
#include <hip/hip_bf16.h>

#define HW 9216          // 96*96
#define NPC 18432        // per-channel element count for BN
#define NELEM 1179648    // 2*64*96*96
// prL strides (bf16 units): o-stride 584 (=576+8), p-stride 4680 (=8*584+8)
// -> phase-2 b128 bank phase = 4*(p+o+i+k) % 32: only free 2-way collisions.
#define PR_O 584
#define PR_P 4680

typedef __attribute__((ext_vector_type(2))) float f32x2;

__device__ __forceinline__ f32x2 fma2(f32x2 a, f32x2 b, f32x2 c) {
#if __has_builtin(__builtin_elementwise_fma)
    return __builtin_elementwise_fma(a, b, c);
#else
    return f32x2{fmaf(a.x, b.x, c.x), fmaf(a.y, b.y, c.y)};
#endif
}
__device__ __forceinline__ float dot8v(f32x2 a0, f32x2 a1, f32x2 a2, f32x2 a3,
                                       f32x2 b0, f32x2 b1, f32x2 b2, f32x2 b3) {
    f32x2 acc = a0 * b0;
    acc = fma2(a1, b1, acc);
    acc = fma2(a2, b2, acc);
    acc = fma2(a3, b3, acc);
    return acc.x + acc.y;
}

template <int CTRL>
__device__ __forceinline__ float dpp_add(float x) {
    int y = __builtin_amdgcn_update_dpp(0, __float_as_int(x), CTRL, 0xF, 0xF, true);
    return x + __int_as_float(y);
}
__device__ __forceinline__ float red_lo(float x) {   // xor 1,2,4
    x = dpp_add<0xB1>(x);
    x = dpp_add<0x4E>(x);
    x = dpp_add<0x141>(x);
    return x;
}
__device__ __forceinline__ float red_hi(float x) {   // xor 8,16,32
    x = dpp_add<0x128>(x);
    x += __shfl_xor(x, 16);
    x += __shfl_xor(x, 32);
    return x;
}

__device__ __forceinline__ int detect_is32(const unsigned short* __restrict__ w1u) {
    int lane = threadIdx.x & 63;
    int bad = 0;
    #pragma unroll
    for (int i = 0; i < 16; ++i) {
        unsigned short u = (unsigned short)(w1u[lane + i * 64] & 0x7FFF);
        bad |= (u >= 0x42C8);   // bf16 |v| >= 100 or NaN/Inf
    }
    return (__ballot(bad) != 0ULL) ? 1 : 0;
}

__device__ __forceinline__ float load_in(const void* p, int idx, int is32) {
    return is32 ? ((const float*)p)[idx]
                : __bfloat162float(((const __hip_bfloat16*)p)[idx]);
}

__device__ __forceinline__ float lo16(unsigned v) { return __int_as_float((int)(v << 16)); }
__device__ __forceinline__ float hi16(unsigned v) { return __int_as_float((int)(v & 0xFFFF0000u)); }

// ---------------------------------------------------------------------------
// prep: 0..575 x-transpose to [b][y][x][c]; 576..863 weight transpose to
// wT[o][j][m][l]; 864 zero BN-stat accumulators.
// ---------------------------------------------------------------------------
__launch_bounds__(256)
__global__ void prep_kernel(const void* __restrict__ x,
                            const void* __restrict__ w1, const void* __restrict__ w2,
                            float* __restrict__ xt,
                            float* __restrict__ wT1, float* __restrict__ wT2,
                            float* __restrict__ statz) {
    __shared__ float tile[64 * 33];
    const int bid = blockIdx.x;
    if (bid < 576) {
        const int is32 = detect_is32((const unsigned short*)w1);
        int xb = bid % 3, y = (bid / 3) % 96, b = bid / 288;
        int x0 = xb * 32;
        for (int e = threadIdx.x; e < 2048; e += 256) {
            int xl = e & 31, c = e >> 5;
            tile[c * 33 + xl] = load_in(x, ((b * 64 + c) * 96 + y) * 96 + x0 + xl, is32);
        }
        __syncthreads();
        for (int f = threadIdx.x; f < 2048; f += 256) {
            int c = f & 63, xl = f >> 6;
            xt[((b * 96 + y) * 96 + x0 + xl) * 64 + c] = tile[c * 33 + xl];
        }
    } else if (bid < 864) {
        const int is32 = detect_is32((const unsigned short*)w1);
        int t = (bid - 576) * 256 + threadIdx.x;   // 0..73727
        const void* w = (t < 36864) ? w1 : w2;
        float* wT = (t < 36864) ? wT1 : wT2;
        int e = t % 36864;
        int l  = e & 7;
        int m  = (e >> 3) & 7;
        int k  = (e >> 6) % 9;
        int oi = e / 576;
        int dy = k / 3, dx = k % 3;
        int src = (((oi * 3 + dy) * 3 + dx) * 8 + l) * 8 + m;
        wT[e] = load_in(w, src, is32);
    } else {
        for (int e = threadIdx.x; e < 2048; e += 256) statz[e] = 0.f;
    }
}

// ---------------------------------------------------------------------------
// Fused capsule conv + routing + BN-stat partials.
// Block = 256 = 4 waves, tile = 3 x-positions x ALL 8 o; wave w -> o in
// {2w, 2w+1}. LDS 32.7 KB -> 5 blocks/CU.
// Phase 1 (lane = jj*8+m): LDS patch rows (register-cached) -> priors -> prL.
// Phase 2 (lane = prob*8+i, prob = o2*3+p): m in-lane, packed u[9], DPP
// i-reduction; lanes 48..63 duplicate prob 0 (no stores).
// ---------------------------------------------------------------------------
__launch_bounds__(256, 5)
__global__ void caps_kernel(const float* __restrict__ in,     // [b][y][x][64]
                            const float* __restrict__ scale,  // layer2 BN fold
                            const float* __restrict__ shift,
                            const float* __restrict__ wT,
                            float* __restrict__ yout,         // [b][y][x][64]
                            float* __restrict__ statL,        // [8 copies][128]
                            int layer1) {
    __shared__ float patch[8 * 120];                          // [i][q=dy*5+col][l]
    __shared__ __align__(16) __hip_bfloat16 prL[3 * PR_P];    // [p][o][i][k][m]
    __shared__ float omI[192];                                // [o][p][m]

    const int x0 = blockIdx.x * 3;
    const int y  = blockIdx.y;
    const int b  = blockIdx.z;
    const int tid = threadIdx.x;

    // ---- stage patch: rows y-1..y+1, cols x0-1..x0+3, 64 channels ----
    for (int e = tid; e < 960; e += 256) {
        int c = e & 63;
        int q = e >> 6;          // 0..14 = dy*5+col
        int dy = q / 5, col = q % 5;
        int yy = y - 1 + dy, xx = x0 - 1 + col;
        float v = 0.f;
        if (yy >= 0 && yy < 96 && xx >= 0 && xx < 96) {
            v = in[((b * 96 + yy) * 96 + xx) * 64 + c];
            if (!layer1) v = v * scale[c] + shift[c];
        }
        patch[(c >> 3) * 120 + q * 8 + (c & 7)] = v;
    }
    __syncthreads();

    const int w    = tid >> 6;     // wave 0..3
    const int lane = tid & 63;

    // ================= Phase 1: priors (lane = jj*8 + m) =================
    {
        const int m  = lane & 7;
        const int jj = lane >> 3;

        float s[2][3] = {{0.f, 0.f, 0.f}, {0.f, 0.f, 0.f}};
        #pragma unroll
        for (int dy = 0; dy < 3; ++dy) {
            f32x2 row2[20];   // 5-col row for this (jj,dy): 40 floats
            const float4* rb = (const float4*)&patch[jj * 120 + dy * 40];
            #pragma unroll
            for (int v = 0; v < 10; ++v) {
                float4 t4 = rb[v];
                row2[2 * v]     = f32x2{t4.x, t4.y};
                row2[2 * v + 1] = f32x2{t4.z, t4.w};
            }
            #pragma unroll
            for (int o2 = 0; o2 < 2; ++o2) {
                const int o = w * 2 + o2;
                const float* wb = wT + o * 4608 + jj * 576 + m * 8;
                #pragma unroll
                for (int dx = 0; dx < 3; ++dx) {
                    const int t = dy * 3 + dx;
                    float4 wa = *(const float4*)(wb + t * 64);
                    float4 wc = *(const float4*)(wb + t * 64 + 4);
                    f32x2 w0{wa.x, wa.y}, w1v{wa.z, wa.w}, w2v{wc.x, wc.y}, w3v{wc.z, wc.w};
                    #pragma unroll
                    for (int p = 0; p < 3; ++p) {
                        const int base = (dx + p) * 4;
                        float a = dot8v(row2[base], row2[base + 1],
                                        row2[base + 2], row2[base + 3],
                                        w0, w1v, w2v, w3v);
                        s[o2][p] += a;
                        prL[p * PR_P + o * PR_O + jj * 72 + t * 8 + m] = __float2bfloat16(a);
                    }
                }
            }
        }
        #pragma unroll
        for (int o2 = 0; o2 < 2; ++o2) {
            #pragma unroll
            for (int p = 0; p < 3; ++p) {
                float v = red_hi(s[o2][p]);          // sum over jj
                if (jj == 0) omI[((w * 2 + o2) * 3 + p) * 8 + m] = v * (1.f / 72.f);
            }
        }
    }
    // No barrier: each wave's prL/omI region is produced & consumed by itself.

    // ========= Phase 2: routing (lane = prob*8 + i, prob = o2*3+p) =========
    const int i    = lane & 7;
    const int probR = lane >> 3;                  // 0..7
    const int valid = (probR < 6);
    const int prob  = valid ? probR : 0;          // lanes 48..63 duplicate prob 0
    const int o2 = prob / 3, p = prob % 3;
    const int o  = w * 2 + o2;

    const __hip_bfloat16* pbase = &prL[p * PR_P + o * PR_O + i * 72];
    uint4 u[9];
    #pragma unroll
    for (int k = 0; k < 9; ++k) u[k] = *(const uint4*)(pbase + k * 8);

    f32x2 om2[4];
    {
        const float* ob = &omI[(o * 3 + p) * 8];
        float4 o0 = *(const float4*)ob;
        float4 o1 = *(const float4*)(ob + 4);
        om2[0] = f32x2{o0.x, o0.y}; om2[1] = f32x2{o0.z, o0.w};
        om2[2] = f32x2{o1.x, o1.y}; om2[3] = f32x2{o1.z, o1.w};
    }
    float n2 = dot8v(om2[0], om2[1], om2[2], om2[3], om2[0], om2[1], om2[2], om2[3]);

    float n1[9];
    #pragma unroll
    for (int it = 0; it < 3; ++it) {
        float se = 0.f;
        f32x2 acc2[4] = {f32x2{0.f, 0.f}, f32x2{0.f, 0.f}, f32x2{0.f, 0.f}, f32x2{0.f, 0.f}};
        #pragma unroll
        for (int k = 0; k < 9; ++k) {
            f32x2 f0{lo16(u[k].x), hi16(u[k].x)};
            f32x2 f1{lo16(u[k].y), hi16(u[k].y)};
            f32x2 f2{lo16(u[k].z), hi16(u[k].z)};
            f32x2 f3{lo16(u[k].w), hi16(u[k].w)};
            if (it == 0) n1[k] = dot8v(f0, f1, f2, f3, f0, f1, f2, f3);
            float d = dot8v(f0, f1, f2, f3, om2[0], om2[1], om2[2], om2[3]);
            float denom = fmaxf(n1[k] + n2 - d, 1e-8f);
            float e = __expf(d * __builtin_amdgcn_rcpf(denom));
            se += e;
            f32x2 ev{e, e};
            acc2[0] = fma2(ev, f0, acc2[0]);
            acc2[1] = fma2(ev, f1, acc2[1]);
            acc2[2] = fma2(ev, f2, acc2[2]);
            acc2[3] = fma2(ev, f3, acc2[3]);
        }
        se = red_lo(se);
        #pragma unroll
        for (int q = 0; q < 4; ++q) {
            acc2[q].x = red_lo(acc2[q].x);
            acc2[q].y = red_lo(acc2[q].y);
        }
        float inv = __builtin_amdgcn_rcpf(se);
        f32x2 iv{inv, inv};
        #pragma unroll
        for (int q = 0; q < 4; ++q) om2[q] = acc2[q] * iv;
        n2 = dot8v(om2[0], om2[1], om2[2], om2[3], om2[0], om2[1], om2[2], om2[3]);
    }

    if (valid && i == 0) {
        float4 o0 = {om2[0].x, om2[0].y, om2[1].x, om2[1].y};
        float4 o1 = {om2[2].x, om2[2].y, om2[3].x, om2[3].y};
        float* dst = &yout[((b * 96 + y) * 96 + x0 + p) * 64 + o * 8];
        *(float4*)dst = o0;
        *(float4*)(dst + 4) = o1;
        *(float4*)&omI[(o * 3 + p) * 8] = o0;      // park finals for BN stats
        *(float4*)&omI[(o * 3 + p) * 8 + 4] = o1;
    }
    __syncthreads();

    // ---- BN stat partials: 64 channels, sum over 3 positions ----
    if (tid < 128) {
        int c = tid & 63, sel = tid >> 6;
        float v = 0.f;
        #pragma unroll
        for (int pp = 0; pp < 3; ++pp) {
            float uu = omI[((c >> 3) * 3 + pp) * 8 + (c & 7)];
            v += sel ? uu * uu : uu;
        }
        int cp = (blockIdx.x + blockIdx.y * 3 + blockIdx.z) & 7;
        atomicAdd(&statL[cp * 128 + sel * 64 + c], v);
    }
}

// ---------------------------------------------------------------------------
// BN params: reduce the 8 stat copies per channel, fold gamma/beta.
// ---------------------------------------------------------------------------
__global__ void bnparams_kernel(const float* __restrict__ statL,
                                const void* __restrict__ gamma,
                                const void* __restrict__ beta,
                                const void* __restrict__ w1,
                                float* __restrict__ sc, float* __restrict__ sh) {
    int is32 = detect_is32((const unsigned short*)w1);
    int c = threadIdx.x;  // 64
    float s = 0.f, ss = 0.f;
    #pragma unroll
    for (int cp = 0; cp < 8; ++cp) {
        s  += statL[cp * 128 + c];
        ss += statL[cp * 128 + 64 + c];
    }
    float mean = s * (1.f / (float)NPC);
    float var  = fmaxf(ss * (1.f / (float)NPC) - mean * mean, 0.f);
    float inv  = rsqrtf(var + 1e-5f);
    float g = load_in(gamma, c, is32) * inv;
    sc[c] = g;
    sh[c] = load_in(beta, c, is32) - mean * g;
}

// ---------------------------------------------------------------------------
// Final: out[b][c][y][x] = x + bn2(y2), tiled transpose from [pos][c].
// ---------------------------------------------------------------------------
__launch_bounds__(256)
__global__ void final_kernel(const void* __restrict__ xin,
                             const float* __restrict__ yt2,
                             const float* __restrict__ sc, const float* __restrict__ sh,
                             const void* __restrict__ w1,
                             void* __restrict__ outp) {
    __shared__ float tile[64 * 33];
    int is32 = detect_is32((const unsigned short*)w1);
    int x0 = blockIdx.x * 32, y = blockIdx.y, b = blockIdx.z;
    for (int e = threadIdx.x; e < 2048; e += 256) {
        int c = e & 63, xl = e >> 6;
        float v = yt2[((b * 96 + y) * 96 + x0 + xl) * 64 + c];
        tile[c * 33 + xl] = v * sc[c] + sh[c];
    }
    __syncthreads();
    for (int f = threadIdx.x; f < 2048; f += 256) {
        int xl = f & 31, c = f >> 5;
        int idx = ((b * 64 + c) * 96 + y) * 96 + x0 + xl;
        float v = load_in(xin, idx, is32) + tile[c * 33 + xl];
        if (is32) ((float*)outp)[idx] = v;
        else      ((__hip_bfloat16*)outp)[idx] = __float2bfloat16(v);
    }
}

// ---------------------------------------------------------------------------
extern "C" void kernel_launch(void* const* d_in, const int* in_sizes, int n_in,
                              void* d_out, int out_size, void* d_ws, size_t ws_size,
                              hipStream_t stream) {
    const void* x  = d_in[0];
    const void* w1 = d_in[1];
    const void* g1 = d_in[2];
    const void* b1 = d_in[3];
    const void* w2 = d_in[4];
    const void* g2 = d_in[5];
    const void* b2 = d_in[6];

    float* ws   = (float*)d_ws;
    float* bufA = ws;                  // xt (layer1 input) / yt2 (alias; xt dead by caps2)
    float* bufB = bufA + NELEM;        // yt1
    float* wT1  = bufB + NELEM;        // 36864
    float* wT2  = wT1 + 36864;         // 36864
    float* statz = wT2 + 36864;        // 2048 (2 layers x 8 copies x 128)
    float* statL1 = statz;
    float* statL2 = statz + 1024;
    float* sc1  = statz + 2048;
    float* sh1  = sc1 + 64;
    float* sc2  = sh1 + 64;
    float* sh2  = sc2 + 64;

    prep_kernel<<<865, 256, 0, stream>>>(x, w1, w2, bufA, wT1, wT2, statz);

    dim3 cgrid(32, 96, 2);   // x-tiles of 3, rows, batch
    caps_kernel<<<cgrid, 256, 0, stream>>>(bufA, nullptr, nullptr, wT1, bufB, statL1, 1);
    bnparams_kernel<<<1, 64, 0, stream>>>(statL1, g1, b1, w1, sc1, sh1);

    caps_kernel<<<cgrid, 256, 0, stream>>>(bufB, sc1, sh1, wT2, bufA, statL2, 0);
    bnparams_kernel<<<1, 64, 0, stream>>>(statL2, g2, b2, w1, sc2, sh2);

    final_kernel<<<dim3(3, 96, 2), 256, 0, stream>>>(x, bufA, sc2, sh2, w1, d_out);
}

// Round 9
// 215.163 us; speedup vs baseline: 2.0794x; 2.0794x over previous
//
#include <hip/hip_runtime.h>
#include <hip/hip_bf16.h>

#define HW 9216          // 96*96
#define NPC 18432        // per-channel element count for BN
#define NELEM 1179648    // 2*64*96*96
#define PSTRIDE 2312     // bf16 units per pos in prL: 4*72*8=2304 +8 pad
#define PATCH_I 196      // floats per i in patch: 24 q * 8 l = 192 +4 (196%32=4 -> jj spread)

typedef __attribute__((ext_vector_type(2))) float f32x2;

__device__ __forceinline__ f32x2 fma2(f32x2 a, f32x2 b, f32x2 c) {
#if __has_builtin(__builtin_elementwise_fma)
    return __builtin_elementwise_fma(a, b, c);
#else
    return f32x2{fmaf(a.x, b.x, c.x), fmaf(a.y, b.y, c.y)};
#endif
}
__device__ __forceinline__ float dot8v(f32x2 a0, f32x2 a1, f32x2 a2, f32x2 a3,
                                       f32x2 b0, f32x2 b1, f32x2 b2, f32x2 b3) {
    f32x2 acc = a0 * b0;
    acc = fma2(a1, b1, acc);
    acc = fma2(a2, b2, acc);
    acc = fma2(a3, b3, acc);
    return acc.x + acc.y;
}

template <int CTRL>
__device__ __forceinline__ float dpp_add(float x) {
    int y = __builtin_amdgcn_update_dpp(0, __float_as_int(x), CTRL, 0xF, 0xF, true);
    return x + __int_as_float(y);
}
__device__ __forceinline__ float red_lo(float x) {   // xor 1,2,4
    x = dpp_add<0xB1>(x);
    x = dpp_add<0x4E>(x);
    x = dpp_add<0x141>(x);
    return x;
}
__device__ __forceinline__ float red_hi(float x) {   // xor 8,16,32
    x = dpp_add<0x128>(x);
    x += __shfl_xor(x, 16);
    x += __shfl_xor(x, 32);
    return x;
}

__device__ __forceinline__ int detect_is32(const unsigned short* __restrict__ w1u) {
    int lane = threadIdx.x & 63;
    int bad = 0;
    #pragma unroll
    for (int i = 0; i < 16; ++i) {
        unsigned short u = (unsigned short)(w1u[lane + i * 64] & 0x7FFF);
        bad |= (u >= 0x42C8);   // bf16 |v| >= 100 or NaN/Inf
    }
    return (__ballot(bad) != 0ULL) ? 1 : 0;
}

__device__ __forceinline__ float load_in(const void* p, int idx, int is32) {
    return is32 ? ((const float*)p)[idx]
                : __bfloat162float(((const __hip_bfloat16*)p)[idx]);
}

__device__ __forceinline__ float lo16(unsigned v) { return __int_as_float((int)(v << 16)); }
__device__ __forceinline__ float hi16(unsigned v) { return __int_as_float((int)(v & 0xFFFF0000u)); }

// ---------------------------------------------------------------------------
// prep: 0..575 x-transpose to [b][y][x][c]; 576..863 weight transpose to
// wT[o][j][m][l]; 864 zero BN-stat accumulators.
// ---------------------------------------------------------------------------
__launch_bounds__(256)
__global__ void prep_kernel(const void* __restrict__ x,
                            const void* __restrict__ w1, const void* __restrict__ w2,
                            float* __restrict__ xt,
                            float* __restrict__ wT1, float* __restrict__ wT2,
                            float* __restrict__ statz) {
    __shared__ float tile[64 * 33];
    const int bid = blockIdx.x;
    if (bid < 576) {
        const int is32 = detect_is32((const unsigned short*)w1);
        int xb = bid % 3, y = (bid / 3) % 96, b = bid / 288;
        int x0 = xb * 32;
        for (int e = threadIdx.x; e < 2048; e += 256) {
            int xl = e & 31, c = e >> 5;
            tile[c * 33 + xl] = load_in(x, ((b * 64 + c) * 96 + y) * 96 + x0 + xl, is32);
        }
        __syncthreads();
        for (int f = threadIdx.x; f < 2048; f += 256) {
            int c = f & 63, xl = f >> 6;
            xt[((b * 96 + y) * 96 + x0 + xl) * 64 + c] = tile[c * 33 + xl];
        }
    } else if (bid < 864) {
        const int is32 = detect_is32((const unsigned short*)w1);
        int t = (bid - 576) * 256 + threadIdx.x;   // 0..73727
        const void* w = (t < 36864) ? w1 : w2;
        float* wT = (t < 36864) ? wT1 : wT2;
        int e = t % 36864;
        int l  = e & 7;
        int m  = (e >> 3) & 7;
        int k  = (e >> 6) % 9;
        int oi = e / 576;
        int dy = k / 3, dx = k % 3;
        int src = (((oi * 3 + dy) * 3 + dx) * 8 + l) * 8 + m;
        wT[e] = load_in(w, src, is32);
    } else {
        for (int e = threadIdx.x; e < 2048; e += 256) statz[e] = 0.f;
    }
}

// ---------------------------------------------------------------------------
// Fused capsule conv + routing + BN-stat partials.
// Block = 256 = 4 waves; wave ol handles o = oh*4+ol for 6 x-positions.
// LDS 34.0 KB + VGPR<=128 via __launch_bounds__(256,4) -> 4 blocks/CU
// (legal VGPR quantum point; (256,5) forced a 48-VGPR spill disaster in R8).
// Phase 1 (lane = jj*8+m): LDS patch rows (register-cached) -> priors -> prL.
// Phase 2 (lane = p*8+i): register priors (fr[36]), m in-lane, DPP i-reduce;
//                         lanes with p>=6 duplicate p=0 (no stores).
// ---------------------------------------------------------------------------
__launch_bounds__(256, 4)
__global__ void caps_kernel(const float* __restrict__ in,     // [b][y][x][64]
                            const float* __restrict__ scale,  // layer2 BN fold
                            const float* __restrict__ shift,
                            const float* __restrict__ wT,
                            float* __restrict__ yout,         // [b][y][x][64]
                            float* __restrict__ statL,        // [8 copies][128]
                            int layer1) {
    __shared__ float patch[8 * PATCH_I];                      // [i][q=dy*8+col][l]
    __shared__ __align__(16) __hip_bfloat16 prL[6 * PSTRIDE]; // [pos][(ol*72+i*9+k)*8+m]
    __shared__ float omI[6 * 32];                             // [pos][ol*8+m]

    const int bx = blockIdx.x;
    const int x0 = (bx >> 1) * 6;
    const int oh = bx & 1;
    const int y  = blockIdx.y;
    const int b  = blockIdx.z;
    const int tid = threadIdx.x;

    // ---- stage patch: rows y-1..y+1, cols x0-1..x0+6, 64 channels ----
    for (int e = tid; e < 1536; e += 256) {
        int c = e & 63;
        int q = e >> 6;          // 0..23 = dy*8+col
        int dy = q >> 3, col = q & 7;
        int yy = y - 1 + dy, xx = x0 - 1 + col;
        float v = 0.f;
        if (yy >= 0 && yy < 96 && xx >= 0 && xx < 96) {
            v = in[((b * 96 + yy) * 96 + xx) * 64 + c];
            if (!layer1) v = v * scale[c] + shift[c];
        }
        patch[(c >> 3) * PATCH_I + q * 8 + (c & 7)] = v;
    }
    __syncthreads();

    const int ol   = tid >> 6;
    const int lane = tid & 63;

    // ================= Phase 1: priors (lane = jj*8 + m) =================
    {
        const int m  = lane & 7;
        const int jj = lane >> 3;
        const float* wb = wT + (oh * 4 + ol) * 4608 + jj * 576 + m * 8;
        __hip_bfloat16* prw = &prL[(ol * 72 + jj * 9) * 8 + m];

        float s[6] = {0.f, 0.f, 0.f, 0.f, 0.f, 0.f};
        #pragma unroll
        for (int dy = 0; dy < 3; ++dy) {
            f32x2 row2[32];   // the 8-col row for this (jj,dy): 64 floats
            const float4* rb = (const float4*)&patch[jj * PATCH_I + dy * 64];
            #pragma unroll
            for (int v = 0; v < 16; ++v) {
                float4 t4 = rb[v];
                row2[2 * v]     = f32x2{t4.x, t4.y};
                row2[2 * v + 1] = f32x2{t4.z, t4.w};
            }
            #pragma unroll
            for (int dx = 0; dx < 3; ++dx) {
                const int t = dy * 3 + dx;
                float4 wa = *(const float4*)(wb + t * 64);
                float4 wc = *(const float4*)(wb + t * 64 + 4);
                f32x2 w0{wa.x, wa.y}, w1v{wa.z, wa.w}, w2v{wc.x, wc.y}, w3v{wc.z, wc.w};
                #pragma unroll
                for (int p = 0; p < 6; ++p) {
                    const int base = (dx + p) * 4;
                    float a = dot8v(row2[base], row2[base + 1], row2[base + 2], row2[base + 3],
                                    w0, w1v, w2v, w3v);
                    s[p] += a;
                    prw[p * PSTRIDE + t * 8] = __float2bfloat16(a);
                }
            }
        }
        #pragma unroll
        for (int p = 0; p < 6; ++p) {
            float v = red_hi(s[p]);
            if (jj == 0) omI[p * 32 + ol * 8 + m] = v * (1.f / 72.f);
        }
    }
    // No barrier: each wave's prL/omI region is produced & consumed by itself.

    // ================= Phase 2: routing (lane = p*8 + i) =================
    const int i  = lane & 7;
    const int pR = lane >> 3;                 // 0..7
    const int valid = (pR < 6);
    const int p  = valid ? pR : 0;            // lanes 48..63 duplicate p=0
    const __hip_bfloat16* pbase = &prL[p * PSTRIDE + (ol * 72 + i * 9) * 8];

    uint4 u[9];
    #pragma unroll
    for (int k = 0; k < 9; ++k) u[k] = *(const uint4*)(pbase + k * 8);

    f32x2 fr[36];
    float n1[9];
    #pragma unroll
    for (int k = 0; k < 9; ++k) {
        fr[4 * k + 0] = f32x2{lo16(u[k].x), hi16(u[k].x)};
        fr[4 * k + 1] = f32x2{lo16(u[k].y), hi16(u[k].y)};
        fr[4 * k + 2] = f32x2{lo16(u[k].z), hi16(u[k].z)};
        fr[4 * k + 3] = f32x2{lo16(u[k].w), hi16(u[k].w)};
        n1[k] = dot8v(fr[4 * k], fr[4 * k + 1], fr[4 * k + 2], fr[4 * k + 3],
                      fr[4 * k], fr[4 * k + 1], fr[4 * k + 2], fr[4 * k + 3]);
    }

    f32x2 om2[4];
    {
        const float* ob = &omI[p * 32 + ol * 8];
        float4 o0 = *(const float4*)ob;
        float4 o1 = *(const float4*)(ob + 4);
        om2[0] = f32x2{o0.x, o0.y}; om2[1] = f32x2{o0.z, o0.w};
        om2[2] = f32x2{o1.x, o1.y}; om2[3] = f32x2{o1.z, o1.w};
    }
    float n2 = dot8v(om2[0], om2[1], om2[2], om2[3], om2[0], om2[1], om2[2], om2[3]);

    #pragma unroll
    for (int it = 0; it < 3; ++it) {
        float se = 0.f;
        f32x2 acc2[4] = {f32x2{0.f, 0.f}, f32x2{0.f, 0.f}, f32x2{0.f, 0.f}, f32x2{0.f, 0.f}};
        #pragma unroll
        for (int k = 0; k < 9; ++k) {
            float d = dot8v(fr[4 * k], fr[4 * k + 1], fr[4 * k + 2], fr[4 * k + 3],
                            om2[0], om2[1], om2[2], om2[3]);
            float denom = fmaxf(n1[k] + n2 - d, 1e-8f);
            float e = __expf(d * __builtin_amdgcn_rcpf(denom));
            se += e;
            f32x2 ev{e, e};
            acc2[0] = fma2(ev, fr[4 * k + 0], acc2[0]);
            acc2[1] = fma2(ev, fr[4 * k + 1], acc2[1]);
            acc2[2] = fma2(ev, fr[4 * k + 2], acc2[2]);
            acc2[3] = fma2(ev, fr[4 * k + 3], acc2[3]);
        }
        se = red_lo(se);
        #pragma unroll
        for (int q = 0; q < 4; ++q) {
            acc2[q].x = red_lo(acc2[q].x);
            acc2[q].y = red_lo(acc2[q].y);
        }
        float inv = __builtin_amdgcn_rcpf(se);
        f32x2 iv{inv, inv};
        #pragma unroll
        for (int q = 0; q < 4; ++q) om2[q] = acc2[q] * iv;
        n2 = dot8v(om2[0], om2[1], om2[2], om2[3], om2[0], om2[1], om2[2], om2[3]);
    }

    if (valid && i == 0) {
        float4 o0 = {om2[0].x, om2[0].y, om2[1].x, om2[1].y};
        float4 o1 = {om2[2].x, om2[2].y, om2[3].x, om2[3].y};
        float* dst = &yout[((b * 96 + y) * 96 + x0 + p) * 64 + (oh * 4 + ol) * 8];
        *(float4*)dst = o0;
        *(float4*)(dst + 4) = o1;
        // park finals for BN-stat reduction
        *(float4*)&omI[p * 32 + ol * 8] = o0;
        *(float4*)&omI[p * 32 + ol * 8 + 4] = o1;
    }
    __syncthreads();

    // ---- BN stat partials: 32 channels (oh half), sum over 6 positions ----
    if (tid < 64) {
        int c32 = tid & 31, sel = tid >> 5;
        float v = 0.f;
        #pragma unroll
        for (int pp = 0; pp < 6; ++pp) {
            float uu = omI[pp * 32 + c32];
            v += sel ? uu * uu : uu;
        }
        int cp = (blockIdx.x + blockIdx.y * 3 + blockIdx.z) & 7;
        atomicAdd(&statL[cp * 128 + sel * 64 + oh * 32 + c32], v);
    }
}

// ---------------------------------------------------------------------------
// BN params (layer 1 only): reduce the 8 stat copies, fold gamma/beta.
// ---------------------------------------------------------------------------
__global__ void bnparams_kernel(const float* __restrict__ statL,
                                const void* __restrict__ gamma,
                                const void* __restrict__ beta,
                                const void* __restrict__ w1,
                                float* __restrict__ sc, float* __restrict__ sh) {
    int is32 = detect_is32((const unsigned short*)w1);
    int c = threadIdx.x;  // 64
    float s = 0.f, ss = 0.f;
    #pragma unroll
    for (int cp = 0; cp < 8; ++cp) {
        s  += statL[cp * 128 + c];
        ss += statL[cp * 128 + 64 + c];
    }
    float mean = s * (1.f / (float)NPC);
    float var  = fmaxf(ss * (1.f / (float)NPC) - mean * mean, 0.f);
    float inv  = rsqrtf(var + 1e-5f);
    float g = load_in(gamma, c, is32) * inv;
    sc[c] = g;
    sh[c] = load_in(beta, c, is32) - mean * g;
}

// ---------------------------------------------------------------------------
// Final: out[b][c][y][x] = x + bn2(y2); bn2 params computed inline per block.
// ---------------------------------------------------------------------------
__launch_bounds__(256)
__global__ void final_kernel(const void* __restrict__ xin,
                             const float* __restrict__ yt2,
                             const float* __restrict__ statL,
                             const void* __restrict__ gamma, const void* __restrict__ beta,
                             const void* __restrict__ w1,
                             void* __restrict__ outp) {
    __shared__ float tile[64 * 33];
    __shared__ float scL[64], shL[64];
    const int is32 = detect_is32((const unsigned short*)w1);
    if (threadIdx.x < 64) {
        int c = threadIdx.x;
        float s = 0.f, ss = 0.f;
        #pragma unroll
        for (int cp = 0; cp < 8; ++cp) {
            s  += statL[cp * 128 + c];
            ss += statL[cp * 128 + 64 + c];
        }
        float mean = s * (1.f / (float)NPC);
        float var  = fmaxf(ss * (1.f / (float)NPC) - mean * mean, 0.f);
        float inv  = rsqrtf(var + 1e-5f);
        float g = load_in(gamma, c, is32) * inv;
        scL[c] = g;
        shL[c] = load_in(beta, c, is32) - mean * g;
    }
    __syncthreads();

    int x0 = blockIdx.x * 32, y = blockIdx.y, b = blockIdx.z;
    for (int e = threadIdx.x; e < 2048; e += 256) {
        int c = e & 63, xl = e >> 6;
        float v = yt2[((b * 96 + y) * 96 + x0 + xl) * 64 + c];
        tile[c * 33 + xl] = v * scL[c] + shL[c];
    }
    __syncthreads();
    for (int f = threadIdx.x; f < 2048; f += 256) {
        int xl = f & 31, c = f >> 5;
        int idx = ((b * 64 + c) * 96 + y) * 96 + x0 + xl;
        float v = load_in(xin, idx, is32) + tile[c * 33 + xl];
        if (is32) ((float*)outp)[idx] = v;
        else      ((__hip_bfloat16*)outp)[idx] = __float2bfloat16(v);
    }
}

// ---------------------------------------------------------------------------
extern "C" void kernel_launch(void* const* d_in, const int* in_sizes, int n_in,
                              void* d_out, int out_size, void* d_ws, size_t ws_size,
                              hipStream_t stream) {
    const void* x  = d_in[0];
    const void* w1 = d_in[1];
    const void* g1 = d_in[2];
    const void* b1 = d_in[3];
    const void* w2 = d_in[4];
    const void* g2 = d_in[5];
    const void* b2 = d_in[6];

    float* ws   = (float*)d_ws;
    float* bufA = ws;                  // xt (layer1 input) / yt2 (alias; xt dead by caps2)
    float* bufB = bufA + NELEM;        // yt1
    float* wT1  = bufB + NELEM;        // 36864
    float* wT2  = wT1 + 36864;         // 36864
    float* statz = wT2 + 36864;        // 2048 (2 layers x 8 copies x 128)
    float* statL1 = statz;
    float* statL2 = statz + 1024;
    float* sc1  = statz + 2048;
    float* sh1  = sc1 + 64;

    prep_kernel<<<865, 256, 0, stream>>>(x, w1, w2, bufA, wT1, wT2, statz);

    dim3 cgrid(32, 96, 2);   // (x-tile of 6) x (o-half), rows, batch
    caps_kernel<<<cgrid, 256, 0, stream>>>(bufA, nullptr, nullptr, wT1, bufB, statL1, 1);
    bnparams_kernel<<<1, 64, 0, stream>>>(statL1, g1, b1, w1, sc1, sh1);

    caps_kernel<<<cgrid, 256, 0, stream>>>(bufB, sc1, sh1, wT2, bufA, statL2, 0);
    final_kernel<<<dim3(3, 96, 2), 256, 0, stream>>>(x, bufA, statL2, g2, b2, w1, d_out);
}